// Round 3
// baseline (797.518 us; speedup 1.0000x reference)
//
#include <hip/hip_runtime.h>

// TurboQuant MSE: y = FWHT(x*sigma)/32; idx = searchsorted(boundaries, y, left);
// x_hat = sigma * FWHT(centroids[idx]) / 32.
// Outputs: [x_hat (N*D f32), indices (N*D, stored as exact float values)].
//
// One wave per row (D=1024, 16 elems/lane). Butterfly stage order matches the
// reference exactly (h ascending, low slot = a+b, high slot = a-b), and every
// transform op is exact or single-rounded identically, so y (and indices) are
// bit-identical to the reference.
//
// Cross-lane stages: m=1,2,4,8 via ds_swizzle + sign-FMA (1 DS + 1 VALU each);
// m=16,32 via v_permlane{16,32}_swap_b32 pair-butterflies (pure VALU pipe).

constexpr int D_DIM  = 1024;
constexpr int N_ROWS = 65536;
constexpr int ELEMS  = 16;
constexpr int WPB    = 4;   // waves per block

typedef float f32x4 __attribute__((ext_vector_type(4)));

__device__ __forceinline__ float sgpr_f(float x) {
    return __int_as_float(__builtin_amdgcn_readfirstlane(__float_as_int(x)));
}

// Butterfly via LDS swizzle (xor mask M within 32-lane halves), combine as
// v = fmaf(v, sgn, partner): lower lanes v+p, upper lanes p-v. Exact.
template<int M>
__device__ __forceinline__ void bfly_swz(float v[ELEMS], float sgn) {
#pragma unroll
    for (int j = 0; j < ELEMS; ++j) {
        float p = __int_as_float(
            __builtin_amdgcn_ds_swizzle(__float_as_int(v[j]), (M << 10) | 0x1F));
        v[j] = fmaf(v[j], sgn, p);
    }
}

// m=16 butterfly on a PAIR of elements using permlane16_swap (VALU pipe):
// swap(a,b): a'={a0,b0,a2,b2}, b'={a1,b1,a3,b3} (16-lane groups).
// s=a'+b' d=a'-b'; swap(s,d): s' = new a, d' = new b.
__device__ __forceinline__ void bfly_pl16(float& a, float& b) {
    asm("v_permlane16_swap_b32 %0, %1" : "+v"(a), "+v"(b));
    float s = a + b;
    float d = a - b;
    asm("v_permlane16_swap_b32 %0, %1" : "+v"(s), "+v"(d));
    a = s;
    b = d;
}

// m=32 butterfly on a pair via permlane32_swap (swaps 32-lane halves).
__device__ __forceinline__ void bfly_pl32(float& a, float& b) {
    asm("v_permlane32_swap_b32 %0, %1" : "+v"(a), "+v"(b));
    float s = a + b;
    float d = a - b;
    asm("v_permlane32_swap_b32 %0, %1" : "+v"(s), "+v"(d));
    a = s;
    b = d;
}

__device__ __forceinline__ void fwht_1024(float v[ELEMS],
                                          float s1, float s2, float s4, float s8) {
    // Intra-lane stages h = 1,2,4,8 (lane holds 16 contiguous elements)
#pragma unroll
    for (int h = 1; h <= 8; h <<= 1) {
#pragma unroll
        for (int i = 0; i < ELEMS; i += 2 * h) {
#pragma unroll
            for (int j = 0; j < h; ++j) {
                float a = v[i + j];
                float b = v[i + j + h];
                v[i + j]     = a + b;
                v[i + j + h] = a - b;
            }
        }
    }
    // Cross-lane stages h = 16..512 (lane-xor masks 1..32, ascending)
    bfly_swz<1>(v, s1);
    bfly_swz<2>(v, s2);
    bfly_swz<4>(v, s4);
    bfly_swz<8>(v, s8);
#pragma unroll
    for (int j = 0; j < ELEMS; j += 2) bfly_pl16(v[j], v[j + 1]);
#pragma unroll
    for (int j = 0; j < ELEMS; j += 2) bfly_pl32(v[j], v[j + 1]);
}

__global__ __launch_bounds__(256, 8) void tq_kernel(
    const float* __restrict__ x,
    const float* __restrict__ sigma,
    const float* __restrict__ centroids,
    const float* __restrict__ boundaries,
    float* __restrict__ out)
{
    __shared__ float c_lds[16];
    if (threadIdx.x < 16) c_lds[threadIdx.x] = centroids[threadIdx.x];
    __syncthreads();

    const int lane = threadIdx.x & 63;
    const size_t row = (size_t)blockIdx.x * WPB + (threadIdx.x >> 6);

    // Boundaries pinned to SGPRs (uniform)
    float bnd[15];
#pragma unroll
    for (int t = 0; t < 15; ++t) bnd[t] = sgpr_f(boundaries[t]);

    const float s1 = (lane & 1) ? -1.0f : 1.0f;
    const float s2 = (lane & 2) ? -1.0f : 1.0f;
    const float s4 = (lane & 4) ? -1.0f : 1.0f;
    const float s8 = (lane & 8) ? -1.0f : 1.0f;

    const f32x4* xr = reinterpret_cast<const f32x4*>(x + row * D_DIM + (size_t)lane * ELEMS);
    const f32x4* sr = reinterpret_cast<const f32x4*>(sigma + (size_t)lane * ELEMS);

    float v[ELEMS];
    unsigned smask = 0;   // bit j = sign bit of sigma[lane*16+j]
#pragma unroll
    for (int q = 0; q < 4; ++q) {
        f32x4 xv = __builtin_nontemporal_load(xr + q);
        f32x4 sv = sr[q];
#pragma unroll
        for (int k = 0; k < 4; ++k) {
            smask |= (__float_as_uint(sv[k]) >> 31) << (4 * q + k);
            v[4 * q + k] = xv[k] * sv[k];   // exact (sigma = +/-1)
        }
    }

    fwht_1024(v, s1, s2, s4, s8);

    // Quantize + store indices immediately (frees registers before 2nd FWHT).
    float* io = out + (size_t)N_ROWS * D_DIM + row * D_DIM + (size_t)lane * ELEMS;
#pragma unroll
    for (int q = 0; q < 4; ++q) {
        f32x4 b;
        float yh[4];
#pragma unroll
        for (int k = 0; k < 4; ++k) {
            const int j = 4 * q + k;
            float y = v[j] * 0.03125f;   // exact 2^-5
            int idx = 0;
#pragma unroll
            for (int t = 0; t < 15; ++t) idx += (bnd[t] < y) ? 1 : 0;
            b[k] = (float)idx;
            yh[k] = c_lds[idx];
        }
#pragma unroll
        for (int k = 0; k < 4; ++k) v[4 * q + k] = yh[k];
        __builtin_nontemporal_store(b, reinterpret_cast<f32x4*>(io) + q);
    }

    fwht_1024(v, s1, s2, s4, s8);

    // x_hat = sigma * (v/32): scale exactly, then flip sign bit per smask (exact).
    float* xo = out + row * D_DIM + (size_t)lane * ELEMS;
#pragma unroll
    for (int q = 0; q < 4; ++q) {
        f32x4 a;
#pragma unroll
        for (int k = 0; k < 4; ++k) {
            const int j = 4 * q + k;
            unsigned sx = (smask >> j) << 31;
            a[k] = __uint_as_float(__float_as_uint(v[j] * 0.03125f) ^ sx);
        }
        __builtin_nontemporal_store(a, reinterpret_cast<f32x4*>(xo) + q);
    }
}

extern "C" void kernel_launch(void* const* d_in, const int* in_sizes, int n_in,
                              void* d_out, int out_size, void* d_ws, size_t ws_size,
                              hipStream_t stream) {
    const float* x          = (const float*)d_in[0];
    const float* sigma      = (const float*)d_in[1];
    const float* centroids  = (const float*)d_in[2];
    const float* boundaries = (const float*)d_in[3];
    float* out = (float*)d_out;

    dim3 grid(N_ROWS / WPB);
    dim3 block(256);
    hipLaunchKernelGGL(tq_kernel, grid, block, 0, stream,
                       x, sigma, centroids, boundaries, out);
}